// Round 4
// baseline (130.084 us; speedup 1.0000x reference)
//
#include <hip/hip_runtime.h>

// Problem constants (from reference setup_inputs)
#define BB 64
#define NN 128
#define DD 128
#define AA 1000
#define KPAD 1024
#define NEG_INF (-9.0e15f)

typedef __attribute__((ext_vector_type(8))) short short8;   // 8 bf16 MFMA frag
typedef __attribute__((ext_vector_type(4))) float floatx4;  // MFMA C/D frag
typedef __attribute__((ext_vector_type(4))) unsigned int uintx4;

__device__ __forceinline__ float bflo(unsigned int u) { return __uint_as_float(u << 16); }
__device__ __forceinline__ float bfhi(unsigned int u) { return __uint_as_float(u & 0xffff0000u); }
// truncating fp32->bf16 pack (cheap; ~2^-9 rel bias, fine vs threshold)
__device__ __forceinline__ unsigned int packbf(float f0, float f1) {
  return (__float_as_uint(f0) >> 16) | (__float_as_uint(f1) & 0xffff0000u);
}
// round-to-nearest-even fp32->bf16
__device__ __forceinline__ unsigned short bf_rne(float f) {
  unsigned int u = __float_as_uint(f);
  return (unsigned short)((u + 0x7fffu + ((u >> 16) & 1u)) >> 16);
}
__device__ __forceinline__ unsigned int packbf_rne(float f0, float f1) {
  return (unsigned int)bf_rne(f0) | ((unsigned int)bf_rne(f1) << 16);
}
__device__ __forceinline__ short8 u2s(uintx4 v) {
  union { uintx4 u; short8 s; } x; x.u = v; return x.s;
}
// bf16-rounded value of x as fp32, optionally abs (msk=0x7fff) — matches
// bflo/bfhi(packbf_rne(..) & 0x7fff7fff) bit-for-bit.
__device__ __forceinline__ float rne_f(float x, unsigned int msk) {
  return __uint_as_float(((unsigned int)bf_rne(x) & msk) << 16);
}

// ---------------------------------------------------------------------------
// Prep (352 blocks x 256) — ALL operand preparation happens here, with full
// parallelism, so fused blocks have (almost) no phases:
//   blocks   0..63  : HTg[b][d][i] = bf16(h^T)  and  Hg[b][i][d] = bf16(h)
//   blocks  64..95  : ET[c][k] = bf16(emb[k][c]), k zero-padded to 1024
//   blocks  96..351 : Asg[b][i][k][d'] — the complete scaled QK A-operand:
//                     d'<128: bf16(h)*0.6*a[d][k]; d'>=128: |bf16(h)|*0.4*a[d][k]
//                     (identical packbf math to the old in-fused As build)
// ---------------------------------------------------------------------------
__global__ __launch_bounds__(256) void prep_kernel(
    const float* __restrict__ hidden, const float* __restrict__ emb,
    const float* __restrict__ amat,
    unsigned short* __restrict__ ET, unsigned short* __restrict__ HTg,
    unsigned short* __restrict__ Hg, unsigned short* __restrict__ Asg)
{
  __shared__ float hsf[NN * 129];
  __shared__ float safk[256];
  const int t = threadIdx.x;
  const int bid = blockIdx.x;
  if (bid < BB) {
    const float* hb = hidden + (size_t)bid * NN * DD;
    #pragma unroll
    for (int u = 0; u < 16; ++u) {
      int e = u * 1024 + t * 4;
      float4 v = *reinterpret_cast<const float4*>(hb + e);
      int r = e >> 7, c = e & 127;
      float* d = &hsf[r * 129 + c];
      d[0] = v.x; d[1] = v.y; d[2] = v.z; d[3] = v.w;
    }
    __syncthreads();
    unsigned short* ht16 = HTg + (size_t)bid * NN * DD;
    #pragma unroll
    for (int u = 0; u < 8; ++u) {  // transpose via LDS columns
      int e = u * 2048 + t * 8;
      int dI = e >> 7, il = e & 127;
      float x[8];
      #pragma unroll
      for (int j = 0; j < 8; ++j) x[j] = hsf[(il + j) * 129 + dI];
      uintx4 o;
      o.x = packbf_rne(x[0], x[1]); o.y = packbf_rne(x[2], x[3]);
      o.z = packbf_rne(x[4], x[5]); o.w = packbf_rne(x[6], x[7]);
      *reinterpret_cast<uintx4*>(ht16 + e) = o;
    }
    // Hg: row-major bf16 h, UNswizzled (consumed by register B-frag loads)
    unsigned short* hg = Hg + (size_t)bid * NN * DD;
    #pragma unroll
    for (int u = 0; u < 8; ++u) {
      int id = u * 256 + t;
      int r = id >> 4, c = id & 15;
      const float* src = &hsf[r * 129 + c * 8];
      uintx4 o;
      o.x = packbf_rne(src[0], src[1]); o.y = packbf_rne(src[2], src[3]);
      o.z = packbf_rne(src[4], src[5]); o.w = packbf_rne(src[6], src[7]);
      *reinterpret_cast<uintx4*>(hg + r * 128 + c * 8) = o;
    }
  } else if (bid < BB + 32) {
    // ET transpose: 32 blocks, 32 k-rows each, coalesced emb reads.
    const int k0 = (bid - BB) * 32;
    #pragma unroll
    for (int u = 0; u < 4; ++u) {
      int e = u * 1024 + t * 4;
      int r = e >> 7, c = e & 127;
      float4 z = {0.f, 0.f, 0.f, 0.f};
      float4 v = (k0 + r < AA)
          ? *reinterpret_cast<const float4*>(emb + (size_t)(k0 + r) * DD + c) : z;
      float* d = &hsf[r * 129 + c];
      d[0] = v.x; d[1] = v.y; d[2] = v.z; d[3] = v.w;
    }
    __syncthreads();
    int c = t >> 1, j0 = (t & 1) * 16;
    float x[16];
    #pragma unroll
    for (int j = 0; j < 16; ++j) x[j] = hsf[(j0 + j) * 129 + c];
    uintx4 o0, o1;
    o0.x = packbf_rne(x[0], x[1]);  o0.y = packbf_rne(x[2], x[3]);
    o0.z = packbf_rne(x[4], x[5]);  o0.w = packbf_rne(x[6], x[7]);
    o1.x = packbf_rne(x[8], x[9]);  o1.y = packbf_rne(x[10], x[11]);
    o1.z = packbf_rne(x[12], x[13]); o1.w = packbf_rne(x[14], x[15]);
    unsigned short* dst = ET + (size_t)c * KPAD + k0 + j0;
    *reinterpret_cast<uintx4*>(dst) = o0;
    *reinterpret_cast<uintx4*>(dst + 8) = o1;
  } else {
    // Asg: 256 blocks, one (b, k) each; 64 KB write per block.
    const int idx = bid - BB - 32;
    const int b = idx >> 2, k = idx & 3;
    safk[t] = ((t & 128) ? 0.4f : 0.6f) * amat[(t & 127) * 4 + k];
    __syncthreads();
    const float* hb = hidden + (size_t)b * NN * DD;
    unsigned short* ag = Asg + ((size_t)b * NN * 4 + k) * 256;  // i-stride 1024
    #pragma unroll
    for (int u = 0; u < 16; ++u) {
      int id = u * 256 + t;
      int i = id >> 5, c = id & 31;
      const float* src = hb + i * DD + (c & 15) * 8;
      float4 v0 = *reinterpret_cast<const float4*>(src);
      float4 v1 = *reinterpret_cast<const float4*>(src + 4);
      unsigned int msk = (c & 16) ? 0x7fffu : 0xffffu;
      float ve0 = rne_f(v0.x, msk), ve1 = rne_f(v0.y, msk);
      float ve2 = rne_f(v0.z, msk), ve3 = rne_f(v0.w, msk);
      float ve4 = rne_f(v1.x, msk), ve5 = rne_f(v1.y, msk);
      float ve6 = rne_f(v1.z, msk), ve7 = rne_f(v1.w, msk);
      const float* sf = &safk[c * 8];
      uintx4 o;
      o.x = packbf(ve0 * sf[0], ve1 * sf[1]);
      o.y = packbf(ve2 * sf[2], ve3 * sf[3]);
      o.z = packbf(ve4 * sf[4], ve5 * sf[5]);
      o.w = packbf(ve6 * sf[6], ve7 * sf[7]);
      *reinterpret_cast<uintx4*>(ag + (size_t)i * 1024 + c * 8) = o;
    }
  }
}

// ---------------------------------------------------------------------------
// Fused kernel, grid = 1024 = exactly 4 blocks/CU (LDS 12.4 KB, VGPR<=128
// via launch_bounds(256,4)), zero tail. wid parity: even -> 16-row attn tile
// (2 barriers total); odd -> 16-row attr-GEMM tile (ZERO LDS, ZERO barriers,
// pure register pipeline). 16 waves/CU of mixed type hide all latencies by
// TLP — no hand-woven slots, no big-LDS staging chains.
// ---------------------------------------------------------------------------
struct FS {
  __align__(16) float Sa[16 * 129];             // 8256 B
  __align__(16) unsigned short W[16 * 128];     // 4096 B
};  // 12352 B

__global__ __launch_bounds__(256, 4) void fused_kernel(
    const int* __restrict__ adj, const float* __restrict__ Aattr,
    const unsigned short* __restrict__ ET, const unsigned short* __restrict__ HTg,
    const unsigned short* __restrict__ Hg, const unsigned short* __restrict__ Asg,
    float* __restrict__ out0, float* __restrict__ out1)
{
  __shared__ FS s;
  const int t = threadIdx.x;
  const int L = t & 63, w = t >> 6;     // wave w = j-quarter / d-quarter / n-quarter
  const int lr = L & 15, lq = L >> 4;   // MFMA lane coords
  // XCD-chunked swizzle (1024 % 8 == 0 -> bijective). XCD x gets wids
  // [128x,128x+128): 64 attn tiles (batches 8x..8x+8 -> Hg/HTg/Asg/adj
  // L2-local) + 64 attr tiles (contiguous 4 MB Aattr chunk).
  const int bid = blockIdx.x;
  const int wid = (bid & 7) * 128 + (bid >> 3);
  const int tile = wid >> 1;

  if ((wid & 1) == 0) {
    // ================= attn tile: b, 16 rows at i0 =================
    const int b = tile >> 3;
    const int i0 = (tile & 7) * 16;

    // adj prefetch (in flight under QK)
    const int* adjb = adj + ((size_t)b * NN + i0) * NN;
    int adjv[8];
    #pragma unroll
    for (int nt = 0; nt < 2; ++nt)
      #pragma unroll
      for (int r = 0; r < 4; ++r)
        adjv[nt * 4 + r] = adjb[(lq * 4 + r) * NN + w * 32 + nt * 16 + lr];

    // QK B-frags straight from global Hg (L2-hot, 8 tiles share each batch)
    const unsigned short* hg = Hg + (size_t)b * NN * DD;
    uintx4 hvq[2][4];
    #pragma unroll
    for (int nt = 0; nt < 2; ++nt)
      #pragma unroll
      for (int q = 0; q < 4; ++q) {
        int jrow = w * 32 + nt * 16 + lr;
        hvq[nt][q] = *reinterpret_cast<const uintx4*>(
            hg + jrow * 128 + (lq + 4 * q) * 8);
      }

    // QK: A-frags straight from precomputed Asg — no LDS, no build phases.
    const unsigned short* ag = Asg + ((size_t)(b * NN + i0 + lr)) * 4 * 256;
    floatx4 acc[4][2];
    #pragma unroll
    for (int k = 0; k < 4; ++k)
      #pragma unroll
      for (int nt = 0; nt < 2; ++nt) acc[k][nt] = floatx4{0.f, 0.f, 0.f, 0.f};

    #pragma unroll
    for (int kt = 0; kt < 8; ++kt) {
      int ca = lq + 4 * kt;
      short8 afr[4];
      #pragma unroll
      for (int k = 0; k < 4; ++k)
        afr[k] = *reinterpret_cast<const short8*>(ag + k * 256 + ca * 8);
      #pragma unroll
      for (int nt = 0; nt < 2; ++nt) {
        uintx4 hv = hvq[nt][kt & 3];
        if (kt >= 4) {
          hv.x &= 0x7fff7fffu; hv.y &= 0x7fff7fffu;
          hv.z &= 0x7fff7fffu; hv.w &= 0x7fff7fffu;
        }
        short8 bfr = u2s(hv);
        #pragma unroll
        for (int k = 0; k < 4; ++k)
          acc[k][nt] = __builtin_amdgcn_mfma_f32_16x16x32_bf16(
              afr[k], bfr, acc[k][nt], 0, 0, 0);
      }
    }

    // PV B-frags (issued here so the latency hides under sel/softmax)
    short8 pvb[2][4];
    const unsigned short* ht = HTg + (size_t)b * NN * DD;
    #pragma unroll
    for (int nt = 0; nt < 2; ++nt)
      #pragma unroll
      for (int kt = 0; kt < 4; ++kt) {
        int dI = w * 32 + nt * 16 + lr;
        pvb[nt][kt] = *reinterpret_cast<const short8*>(
            ht + dI * 128 + kt * 32 + lq * 8);
      }

    // in-register adj selection; C/D: col=lane&15, row=(lane>>4)*4+reg
    #pragma unroll
    for (int nt = 0; nt < 2; ++nt)
      #pragma unroll
      for (int r = 0; r < 4; ++r) {
        int ii = lq * 4 + r;
        int j = w * 32 + nt * 16 + lr;
        int ad = adjv[nt * 4 + r];
        float al = NEG_INF;
        al = (ad == 1) ? acc[0][nt][r] : al;
        al = (ad == 2) ? acc[1][nt][r] : al;
        al = (ad == 3) ? acc[2][nt][r] : al;
        al = (ad == 4) ? acc[3][nt][r] : al;
        s.Sa[ii * 129 + j] = al;
      }
    __syncthreads();  // barrier 1 of 2

    // softmax: one full row per wave (lane holds j=L and j=L+64)
    #pragma unroll
    for (int p = 0; p < 4; ++p) {
      int ii = w * 4 + p;
      float a1 = s.Sa[ii * 129 + L];
      float a2 = s.Sa[ii * 129 + 64 + L];
      float m = fmaxf(a1, a2);
      #pragma unroll
      for (int off = 32; off > 0; off >>= 1) m = fmaxf(m, __shfl_xor(m, off, 64));
      // all-masked row: a-m==0 -> uniform (matches jax); clamp guards exp
      float e1 = __expf(fmaxf(a1 - m, -80.f));
      float e2 = __expf(fmaxf(a2 - m, -80.f));
      float ss = e1 + e2;
      #pragma unroll
      for (int off = 32; off > 0; off >>= 1) ss += __shfl_xor(ss, off, 64);
      float inv = 1.f / ss;
      int j2 = L + 64;
      s.W[ii * 128 + (((L >> 3) ^ ii) << 3) + (L & 7)] = bf_rne(e1 * inv);
      s.W[ii * 128 + (((j2 >> 3) ^ ii) << 3) + (j2 & 7)] = bf_rne(e2 * inv);
    }
    __syncthreads();  // barrier 2 of 2

    // PV: out[i][d] = sum_j W[i,j] * h[j,d]
    floatx4 oacc0 = floatx4{0.f, 0.f, 0.f, 0.f};
    floatx4 oacc1 = floatx4{0.f, 0.f, 0.f, 0.f};
    #pragma unroll
    for (int kt = 0; kt < 4; ++kt) {
      int c = lq + 4 * kt;
      short8 wf = *reinterpret_cast<const short8*>(
          &s.W[lr * 128 + ((c ^ lr) << 3)]);
      oacc0 = __builtin_amdgcn_mfma_f32_16x16x32_bf16(wf, pvb[0][kt], oacc0, 0, 0, 0);
      oacc1 = __builtin_amdgcn_mfma_f32_16x16x32_bf16(wf, pvb[1][kt], oacc1, 0, 0, 0);
    }
    float* ob = out0 + ((size_t)b * NN + i0) * DD;
    #pragma unroll
    for (int r = 0; r < 4; ++r) {
      ob[(lq * 4 + r) * DD + w * 32 + lr] = oacc0[r];
      ob[(lq * 4 + r) * DD + w * 32 + 16 + lr] = oacc1[r];
    }
  } else {
    // ========= attr tile: 16 rows at r0, zero LDS / zero barriers =========
    const int r0 = tile * 16;
    const float* arow = Aattr + (size_t)(r0 + lr) * AA;   // per-lane A row
    const unsigned short* e0 = ET + (size_t)(w * 32 + lr) * KPAD;
    const unsigned short* e1 = ET + (size_t)(w * 32 + 16 + lr) * KPAD;

    float4 paA[4], paB[4];   // [ks*2 + half] fp32 A pieces
    uintx4 peA[4], peB[4];   // [ks*2 + nt]   bf16 ET frags
    floatx4 acc0 = floatx4{0.f, 0.f, 0.f, 0.f};
    floatx4 acc1 = floatx4{0.f, 0.f, 0.f, 0.f};

#define AFETCH(PA, PE, IT) do {                                              \
    int kb = (IT) * 64;                                                      \
    float4 z = {0.f, 0.f, 0.f, 0.f};                                        \
    _Pragma("unroll")                                                        \
    for (int ks = 0; ks < 2; ++ks) {                                         \
      int k4 = kb + (lq + 4 * ks) * 8;                                       \
      PA[ks * 2 + 0] = (k4 < AA) ? *reinterpret_cast<const float4*>(arow + k4) : z; \
      PA[ks * 2 + 1] = (k4 + 4 < AA) ? *reinterpret_cast<const float4*>(arow + k4 + 4) : z; \
      PE[ks * 2 + 0] = *reinterpret_cast<const uintx4*>(e0 + k4);            \
      PE[ks * 2 + 1] = *reinterpret_cast<const uintx4*>(e1 + k4);            \
    }                                                                        \
  } while (0)

    // body: move operands to frag regs, refill the set (2 iters ahead), MFMA
#define ABODY(PA, PE, IT) do {                                               \
    short8 af0, af1, bf00, bf01, bf10, bf11;                                 \
    {                                                                        \
      uintx4 a0, a1;                                                         \
      a0.x = packbf(PA[0].x, PA[0].y); a0.y = packbf(PA[0].z, PA[0].w);      \
      a0.z = packbf(PA[1].x, PA[1].y); a0.w = packbf(PA[1].z, PA[1].w);      \
      a1.x = packbf(PA[2].x, PA[2].y); a1.y = packbf(PA[2].z, PA[2].w);      \
      a1.z = packbf(PA[3].x, PA[3].y); a1.w = packbf(PA[3].z, PA[3].w);      \
      af0 = u2s(a0); af1 = u2s(a1);                                          \
      bf00 = u2s(PE[0]); bf01 = u2s(PE[1]);                                  \
      bf10 = u2s(PE[2]); bf11 = u2s(PE[3]);                                  \
    }                                                                        \
    if ((IT) < 14) AFETCH(PA, PE, (IT) + 2);                                 \
    acc0 = __builtin_amdgcn_mfma_f32_16x16x32_bf16(af0, bf00, acc0, 0, 0, 0); \
    acc1 = __builtin_amdgcn_mfma_f32_16x16x32_bf16(af0, bf01, acc1, 0, 0, 0); \
    acc0 = __builtin_amdgcn_mfma_f32_16x16x32_bf16(af1, bf10, acc0, 0, 0, 0); \
    acc1 = __builtin_amdgcn_mfma_f32_16x16x32_bf16(af1, bf11, acc1, 0, 0, 0); \
  } while (0)

    AFETCH(paA, peA, 0);
    AFETCH(paB, peB, 1);
    #pragma unroll
    for (int ith = 0; ith < 8; ++ith) {
      ABODY(paA, peA, 2 * ith);
      ABODY(paB, peB, 2 * ith + 1);
    }
#undef AFETCH
#undef ABODY

    float* ob = out1 + (size_t)r0 * DD;
    #pragma unroll
    for (int r = 0; r < 4; ++r) {
      ob[(lq * 4 + r) * DD + w * 32 + lr] = acc0[r];
      ob[(lq * 4 + r) * DD + w * 32 + 16 + lr] = acc1[r];
    }
  }
}

extern "C" void kernel_launch(void* const* d_in, const int* in_sizes, int n_in,
                              void* d_out, int out_size, void* d_ws, size_t ws_size,
                              hipStream_t stream) {
  const float* hidden = (const float*)d_in[0];  // [64,128,128] fp32
  const int*   adj    = (const int*)d_in[1];    // [64,128,128] int32
  const float* amat   = (const float*)d_in[2];  // [128,4] fp32
  const float* Aattr  = (const float*)d_in[3];  // [64,128,1000] fp32
  const float* emb    = (const float*)d_in[4];  // [1000,128] fp32

  float* out0 = (float*)d_out;                  // output    [64,128,128] fp32
  float* out1 = out0 + (size_t)BB * NN * DD;    // attr_sess [64,128,128] fp32

  // d_ws layout (rebuilt every call): bf16 operand copies, ~21.2 MB total
  unsigned short* ET  = (unsigned short*)d_ws;        // [128][1024]
  unsigned short* HTg = ET + (size_t)DD * KPAD;       // [64][128][128] h^T
  unsigned short* Hg  = HTg + (size_t)BB * NN * DD;   // [64][128][128] h
  unsigned short* Asg = Hg + (size_t)BB * NN * DD;    // [64][128][4][256]

  prep_kernel<<<BB + 32 + 256, 256, 0, stream>>>(hidden, emb, amat,
                                                 ET, HTg, Hg, Asg);
  fused_kernel<<<1024, 256, 0, stream>>>(adj, Aattr, ET, HTg, Hg, Asg,
                                         out0, out1);
}

// Round 5
// 124.964 us; speedup vs baseline: 1.0410x; 1.0410x over previous
//
#include <hip/hip_runtime.h>

// Problem constants (from reference setup_inputs)
#define BB 64
#define NN 128
#define DD 128
#define AA 1000
#define KPAD 1024
#define NEG_INF (-9.0e15f)

typedef __attribute__((ext_vector_type(8))) short short8;   // 8 bf16 MFMA frag
typedef __attribute__((ext_vector_type(4))) float floatx4;  // MFMA C/D frag
typedef __attribute__((ext_vector_type(4))) unsigned int uintx4;

__device__ __forceinline__ float bflo(unsigned int u) { return __uint_as_float(u << 16); }
__device__ __forceinline__ float bfhi(unsigned int u) { return __uint_as_float(u & 0xffff0000u); }
// truncating fp32->bf16 pack (cheap; ~2^-9 rel bias, fine vs threshold)
__device__ __forceinline__ unsigned int packbf(float f0, float f1) {
  return (__float_as_uint(f0) >> 16) | (__float_as_uint(f1) & 0xffff0000u);
}
// round-to-nearest-even fp32->bf16
__device__ __forceinline__ unsigned short bf_rne(float f) {
  unsigned int u = __float_as_uint(f);
  return (unsigned short)((u + 0x7fffu + ((u >> 16) & 1u)) >> 16);
}
__device__ __forceinline__ unsigned int packbf_rne(float f0, float f1) {
  return (unsigned int)bf_rne(f0) | ((unsigned int)bf_rne(f1) << 16);
}
__device__ __forceinline__ short8 u2s(uintx4 v) {
  union { uintx4 u; short8 s; } x; x.u = v; return x.s;
}
// bf16-rounded value of x as fp32, optionally abs (msk=0x7fff) — matches
// bflo/bfhi(packbf_rne(..) & 0x7fff7fff) bit-for-bit.
__device__ __forceinline__ float rne_f(float x, unsigned int msk) {
  return __uint_as_float(((unsigned int)bf_rne(x) & msk) << 16);
}

// ---------------------------------------------------------------------------
// Prep (352 blocks x 256):
//   blocks   0..63  : HTg[b][d][i] = bf16(h^T)  and  Hg[b][i][d] = bf16(h)
//   blocks  64..95  : ET[c][k] = bf16(emb[k][c]), k zero-padded to 1024
//   blocks  96..351 : Asg — scaled QK A-operand, stored as the EXACT linear
//                     LDS image the attn kernel stages (tile-major, row
//                     swizzle c^(i&15)). One block per (b, 32-row quarter),
//                     all 4 edge types -> hidden read once (no 4x re-read).
// ---------------------------------------------------------------------------
__global__ __launch_bounds__(256) void prep_kernel(
    const float* __restrict__ hidden, const float* __restrict__ emb,
    const float* __restrict__ amat,
    unsigned short* __restrict__ ET, unsigned short* __restrict__ HTg,
    unsigned short* __restrict__ Hg, unsigned short* __restrict__ Asg)
{
  __shared__ float hsf[NN * 129];
  __shared__ float safk[1024];
  const int t = threadIdx.x;
  const int bid = blockIdx.x;
  if (bid < BB) {
    const float* hb = hidden + (size_t)bid * NN * DD;
    #pragma unroll
    for (int u = 0; u < 16; ++u) {
      int e = u * 1024 + t * 4;
      float4 v = *reinterpret_cast<const float4*>(hb + e);
      int r = e >> 7, c = e & 127;
      float* d = &hsf[r * 129 + c];
      d[0] = v.x; d[1] = v.y; d[2] = v.z; d[3] = v.w;
    }
    __syncthreads();
    unsigned short* ht16 = HTg + (size_t)bid * NN * DD;
    #pragma unroll
    for (int u = 0; u < 8; ++u) {  // transpose via LDS columns
      int e = u * 2048 + t * 8;
      int dI = e >> 7, il = e & 127;
      float x[8];
      #pragma unroll
      for (int j = 0; j < 8; ++j) x[j] = hsf[(il + j) * 129 + dI];
      uintx4 o;
      o.x = packbf_rne(x[0], x[1]); o.y = packbf_rne(x[2], x[3]);
      o.z = packbf_rne(x[4], x[5]); o.w = packbf_rne(x[6], x[7]);
      *reinterpret_cast<uintx4*>(ht16 + e) = o;
    }
    // Hg: row-major bf16 h, unswizzled (consumed by register B-frag loads)
    unsigned short* hg = Hg + (size_t)bid * NN * DD;
    #pragma unroll
    for (int u = 0; u < 8; ++u) {
      int id = u * 256 + t;
      int r = id >> 4, c = id & 15;
      const float* src = &hsf[r * 129 + c * 8];
      uintx4 o;
      o.x = packbf_rne(src[0], src[1]); o.y = packbf_rne(src[2], src[3]);
      o.z = packbf_rne(src[4], src[5]); o.w = packbf_rne(src[6], src[7]);
      *reinterpret_cast<uintx4*>(hg + r * 128 + c * 8) = o;
    }
  } else if (bid < BB + 32) {
    // ET transpose: 32 blocks, 32 k-rows each, coalesced emb reads.
    const int k0 = (bid - BB) * 32;
    #pragma unroll
    for (int u = 0; u < 4; ++u) {
      int e = u * 1024 + t * 4;
      int r = e >> 7, c = e & 127;
      float4 z = {0.f, 0.f, 0.f, 0.f};
      float4 v = (k0 + r < AA)
          ? *reinterpret_cast<const float4*>(emb + (size_t)(k0 + r) * DD + c) : z;
      float* d = &hsf[r * 129 + c];
      d[0] = v.x; d[1] = v.y; d[2] = v.z; d[3] = v.w;
    }
    __syncthreads();
    int c = t >> 1, j0 = (t & 1) * 16;
    float x[16];
    #pragma unroll
    for (int j = 0; j < 16; ++j) x[j] = hsf[(j0 + j) * 129 + c];
    uintx4 o0, o1;
    o0.x = packbf_rne(x[0], x[1]);  o0.y = packbf_rne(x[2], x[3]);
    o0.z = packbf_rne(x[4], x[5]);  o0.w = packbf_rne(x[6], x[7]);
    o1.x = packbf_rne(x[8], x[9]);  o1.y = packbf_rne(x[10], x[11]);
    o1.z = packbf_rne(x[12], x[13]); o1.w = packbf_rne(x[14], x[15]);
    unsigned short* dst = ET + (size_t)c * KPAD + k0 + j0;
    *reinterpret_cast<uintx4*>(dst) = o0;
    *reinterpret_cast<uintx4*>(dst + 8) = o1;
  } else {
    // Asg: 256 blocks, one per (b, 32-row quarter), all 4 edge types.
    const int idx = bid - BB - 32;
    const int b = idx >> 2, iq = idx & 3;
    // safk[k*256 + d'] = (d'<128 ? 0.6 : 0.4) * a[d'&127][k]
    #pragma unroll
    for (int q = 0; q < 4; ++q) {
      int idq = q * 256 + t;
      int k = idq >> 8, dp = idq & 255;
      safk[idq] = ((dp & 128) ? 0.4f : 0.6f) * amat[(dp & 127) * 4 + k];
    }
    __syncthreads();
    const float* hb = hidden + ((size_t)b * NN + iq * 32) * DD;
    unsigned short* ag = Asg + ((size_t)b * 8 + iq * 2) * 16384;
    // 32 il x 4 k x 32 c 16B-stores = 4096 -> 16 per thread
    #pragma unroll
    for (int v = 0; v < 16; ++v) {
      int id = v * 256 + t;
      int il = id >> 7, k = (id >> 5) & 3, c = id & 31;
      const float* src = hb + il * DD + (c & 15) * 8;
      float4 v0 = *reinterpret_cast<const float4*>(src);
      float4 v1 = *reinterpret_cast<const float4*>(src + 4);
      unsigned int msk = (c & 16) ? 0x7fffu : 0xffffu;
      float ve0 = rne_f(v0.x, msk), ve1 = rne_f(v0.y, msk);
      float ve2 = rne_f(v0.z, msk), ve3 = rne_f(v0.w, msk);
      float ve4 = rne_f(v1.x, msk), ve5 = rne_f(v1.y, msk);
      float ve6 = rne_f(v1.z, msk), ve7 = rne_f(v1.w, msk);
      const float* sf = &safk[k * 256 + c * 8];
      uintx4 o;
      o.x = packbf(ve0 * sf[0], ve1 * sf[1]);
      o.y = packbf(ve2 * sf[2], ve3 * sf[3]);
      o.z = packbf(ve4 * sf[4], ve5 * sf[5]);
      o.w = packbf(ve6 * sf[6], ve7 * sf[7]);
      *reinterpret_cast<uintx4*>(
          ag + (il >> 4) * 16384 + k * 4096 + (il & 15) * 256
             + ((c ^ (il & 15)) << 3)) = o;
    }
  }
}

// ---------------------------------------------------------------------------
// Attn kernel: 512 blocks (b, 16-row i-tile). launch_bounds(256,2) so the
// ~130-VGPR live set (hvq/pvb/acc/adjv) stays register-resident — R4's
// (256,4) squeezed to 64 VGPR and serialized every fragment load (warm-replay
// dur was unchanged at ~52us with zero FETCH: pure dependency chain).
// As comes precomputed from prep; staged with one bulk linear LDS copy;
// QK is the round-0-proven pure ds_read_b128 + MFMA loop.
// ---------------------------------------------------------------------------
__global__ __launch_bounds__(256, 2) void attn_kernel(
    const int* __restrict__ adj,
    const unsigned short* __restrict__ HTg, const unsigned short* __restrict__ Hg,
    const unsigned short* __restrict__ Asg, float* __restrict__ out0)
{
  __shared__ union {
    unsigned short As[4 * 16 * 256];                       // 32768 B
    struct { float Sa[16 * 129]; unsigned short W[16 * 128]; } sw;
  } uu;
  const int t = threadIdx.x;
  const int L = t & 63, w = t >> 6;
  const int lr = L & 15, lq = L >> 4;
  // XCD-chunked bijective swizzle (512 % 8 == 0): 8 consecutive tiles of a
  // batch land on one XCD (Hg/HTg/Asg/adj L2-local).
  const int bid = blockIdx.x;
  const int wid = (bid & 7) * 64 + (bid >> 3);
  const int b = wid >> 3;
  const int i0 = (wid & 7) * 16;

  // ---- bulk As stage: 8 independent 16B loads/thread + linear ds_write ----
  const unsigned short* ags = Asg + (size_t)wid * 16384;
  uintx4 asv[8];
  #pragma unroll
  for (int u = 0; u < 8; ++u)
    asv[u] = *reinterpret_cast<const uintx4*>(ags + (u * 256 + t) * 8);

  // ---- adj prefetch ----
  const int* adjb = adj + ((size_t)b * NN + i0) * NN;
  int adjv[8];
  #pragma unroll
  for (int nt = 0; nt < 2; ++nt)
    #pragma unroll
    for (int r = 0; r < 4; ++r)
      adjv[nt * 4 + r] = adjb[(lq * 4 + r) * NN + w * 32 + nt * 16 + lr];

  // ---- QK B-frags from Hg (registers) ----
  const unsigned short* hg = Hg + (size_t)b * NN * DD;
  uintx4 hvq[2][4];
  #pragma unroll
  for (int nt = 0; nt < 2; ++nt)
    #pragma unroll
    for (int q = 0; q < 4; ++q) {
      int jrow = w * 32 + nt * 16 + lr;
      hvq[nt][q] = *reinterpret_cast<const uintx4*>(
          hg + jrow * 128 + (lq + 4 * q) * 8);
    }

  // ---- PV B-frags from HTg (registers) ----
  short8 pvb[2][4];
  const unsigned short* ht = HTg + (size_t)b * NN * DD;
  #pragma unroll
  for (int nt = 0; nt < 2; ++nt)
    #pragma unroll
    for (int kt = 0; kt < 4; ++kt) {
      int dI = w * 32 + nt * 16 + lr;
      pvb[nt][kt] = *reinterpret_cast<const short8*>(
          ht + dI * 128 + kt * 32 + lq * 8);
    }

  #pragma unroll
  for (int u = 0; u < 8; ++u)
    *reinterpret_cast<uintx4*>(&uu.As[(u * 256 + t) * 8]) = asv[u];
  __syncthreads();  // barrier 1: As staged

  // ---- QK: pure ds_read_b128 + MFMA ----
  floatx4 acc[4][2];
  #pragma unroll
  for (int k = 0; k < 4; ++k)
    #pragma unroll
    for (int nt = 0; nt < 2; ++nt) acc[k][nt] = floatx4{0.f, 0.f, 0.f, 0.f};

  #pragma unroll
  for (int kt = 0; kt < 8; ++kt) {
    int ca = lq + 4 * kt;
    short8 afr[4];
    #pragma unroll
    for (int k = 0; k < 4; ++k)
      afr[k] = *reinterpret_cast<const short8*>(
          &uu.As[k * 4096 + lr * 256 + ((ca ^ lr) << 3)]);
    #pragma unroll
    for (int nt = 0; nt < 2; ++nt) {
      uintx4 hv = hvq[nt][kt & 3];
      if (kt >= 4) {
        hv.x &= 0x7fff7fffu; hv.y &= 0x7fff7fffu;
        hv.z &= 0x7fff7fffu; hv.w &= 0x7fff7fffu;
      }
      short8 bfr = u2s(hv);
      #pragma unroll
      for (int k = 0; k < 4; ++k)
        acc[k][nt] = __builtin_amdgcn_mfma_f32_16x16x32_bf16(
            afr[k], bfr, acc[k][nt], 0, 0, 0);
    }
  }
  __syncthreads();  // barrier 2: As reads done, Sa/W may overlay

  // ---- in-register adj selection; C/D: col=lane&15, row=(lane>>4)*4+reg ----
  #pragma unroll
  for (int nt = 0; nt < 2; ++nt)
    #pragma unroll
    for (int r = 0; r < 4; ++r) {
      int ii = lq * 4 + r;
      int j = w * 32 + nt * 16 + lr;
      int ad = adjv[nt * 4 + r];
      float al = NEG_INF;
      al = (ad == 1) ? acc[0][nt][r] : al;
      al = (ad == 2) ? acc[1][nt][r] : al;
      al = (ad == 3) ? acc[2][nt][r] : al;
      al = (ad == 4) ? acc[3][nt][r] : al;
      uu.sw.Sa[ii * 129 + j] = al;
    }
  __syncthreads();  // barrier 3

  // ---- softmax: one full row per wave (lane holds j=L and j=L+64) ----
  #pragma unroll
  for (int p = 0; p < 4; ++p) {
    int ii = w * 4 + p;
    float a1 = uu.sw.Sa[ii * 129 + L];
    float a2 = uu.sw.Sa[ii * 129 + 64 + L];
    float m = fmaxf(a1, a2);
    #pragma unroll
    for (int off = 32; off > 0; off >>= 1) m = fmaxf(m, __shfl_xor(m, off, 64));
    // all-masked row: a-m==0 -> uniform (matches jax); clamp guards exp
    float e1 = __expf(fmaxf(a1 - m, -80.f));
    float e2 = __expf(fmaxf(a2 - m, -80.f));
    float ss = e1 + e2;
    #pragma unroll
    for (int off = 32; off > 0; off >>= 1) ss += __shfl_xor(ss, off, 64);
    float inv = 1.f / ss;
    int j2 = L + 64;
    uu.sw.W[ii * 128 + (((L >> 3) ^ ii) << 3) + (L & 7)] = bf_rne(e1 * inv);
    uu.sw.W[ii * 128 + (((j2 >> 3) ^ ii) << 3) + (j2 & 7)] = bf_rne(e2 * inv);
  }
  __syncthreads();  // barrier 4

  // ---- PV ----
  floatx4 oacc0 = floatx4{0.f, 0.f, 0.f, 0.f};
  floatx4 oacc1 = floatx4{0.f, 0.f, 0.f, 0.f};
  #pragma unroll
  for (int kt = 0; kt < 4; ++kt) {
    int c = lq + 4 * kt;
    short8 wf = *reinterpret_cast<const short8*>(
        &uu.sw.W[lr * 128 + ((c ^ lr) << 3)]);
    oacc0 = __builtin_amdgcn_mfma_f32_16x16x32_bf16(wf, pvb[0][kt], oacc0, 0, 0, 0);
    oacc1 = __builtin_amdgcn_mfma_f32_16x16x32_bf16(wf, pvb[1][kt], oacc1, 0, 0, 0);
  }
  float* ob = out0 + ((size_t)b * NN + i0) * DD;
  #pragma unroll
  for (int r = 0; r < 4; ++r) {
    ob[(lq * 4 + r) * DD + w * 32 + lr] = oacc0[r];
    ob[(lq * 4 + r) * DD + w * 32 + 16 + lr] = oacc1[r];
  }
}

// ---------------------------------------------------------------------------
// Attr kernel: 512 blocks, 16-row tiles, zero LDS / zero barriers, 3-deep
// named register prefetch (A/B/C). launch_bounds(256,2) -> sets stay in
// registers (3x32 + acc + addr ~ 130 VGPR).
// ---------------------------------------------------------------------------
__global__ __launch_bounds__(256, 2) void attr_kernel(
    const float* __restrict__ Aattr, const unsigned short* __restrict__ ET,
    float* __restrict__ out1)
{
  const int t = threadIdx.x;
  const int L = t & 63, w = t >> 6;
  const int lr = L & 15, lq = L >> 4;
  const int bid = blockIdx.x;
  const int wid = (bid & 7) * 64 + (bid >> 3);
  const int r0 = wid * 16;

  const float* arow = Aattr + (size_t)(r0 + lr) * AA;   // per-lane A row
  const unsigned short* e0 = ET + (size_t)(w * 32 + lr) * KPAD;
  const unsigned short* e1 = ET + (size_t)(w * 32 + 16 + lr) * KPAD;

  float4 paA[4], paB[4], paC[4];   // [ks*2 + half] fp32 A pieces
  uintx4 peA[4], peB[4], peC[4];   // [ks*2 + nt]   bf16 ET frags
  floatx4 acc0 = floatx4{0.f, 0.f, 0.f, 0.f};
  floatx4 acc1 = floatx4{0.f, 0.f, 0.f, 0.f};

#define AFETCH(PA, PE, IT) do {                                              \
    int kb = (IT) * 64;                                                      \
    float4 z = {0.f, 0.f, 0.f, 0.f};                                        \
    _Pragma("unroll")                                                        \
    for (int ks = 0; ks < 2; ++ks) {                                         \
      int k4 = kb + (lq + 4 * ks) * 8;                                       \
      PA[ks * 2 + 0] = (k4 < AA) ? *reinterpret_cast<const float4*>(arow + k4) : z; \
      PA[ks * 2 + 1] = (k4 + 4 < AA) ? *reinterpret_cast<const float4*>(arow + k4 + 4) : z; \
      PE[ks * 2 + 0] = *reinterpret_cast<const uintx4*>(e0 + k4);            \
      PE[ks * 2 + 1] = *reinterpret_cast<const uintx4*>(e1 + k4);            \
    }                                                                        \
  } while (0)

#define ABODY(PA, PE, IT) do {                                               \
    short8 af0, af1, bf00, bf01, bf10, bf11;                                 \
    {                                                                        \
      uintx4 a0, a1;                                                         \
      a0.x = packbf(PA[0].x, PA[0].y); a0.y = packbf(PA[0].z, PA[0].w);      \
      a0.z = packbf(PA[1].x, PA[1].y); a0.w = packbf(PA[1].z, PA[1].w);      \
      a1.x = packbf(PA[2].x, PA[2].y); a1.y = packbf(PA[2].z, PA[2].w);      \
      a1.z = packbf(PA[3].x, PA[3].y); a1.w = packbf(PA[3].z, PA[3].w);      \
      af0 = u2s(a0); af1 = u2s(a1);                                          \
      bf00 = u2s(PE[0]); bf01 = u2s(PE[1]);                                  \
      bf10 = u2s(PE[2]); bf11 = u2s(PE[3]);                                  \
    }                                                                        \
    if ((IT) < 13) AFETCH(PA, PE, (IT) + 3);                                 \
    acc0 = __builtin_amdgcn_mfma_f32_16x16x32_bf16(af0, bf00, acc0, 0, 0, 0); \
    acc1 = __builtin_amdgcn_mfma_f32_16x16x32_bf16(af0, bf01, acc1, 0, 0, 0); \
    acc0 = __builtin_amdgcn_mfma_f32_16x16x32_bf16(af1, bf10, acc0, 0, 0, 0); \
    acc1 = __builtin_amdgcn_mfma_f32_16x16x32_bf16(af1, bf11, acc1, 0, 0, 0); \
  } while (0)

  AFETCH(paA, peA, 0);
  AFETCH(paB, peB, 1);
  AFETCH(paC, peC, 2);
  ABODY(paA, peA, 0);  ABODY(paB, peB, 1);  ABODY(paC, peC, 2);
  ABODY(paA, peA, 3);  ABODY(paB, peB, 4);  ABODY(paC, peC, 5);
  ABODY(paA, peA, 6);  ABODY(paB, peB, 7);  ABODY(paC, peC, 8);
  ABODY(paA, peA, 9);  ABODY(paB, peB, 10); ABODY(paC, peC, 11);
  ABODY(paA, peA, 12); ABODY(paB, peB, 13); ABODY(paC, peC, 14);
  ABODY(paA, peA, 15);
#undef AFETCH
#undef ABODY

  float* ob = out1 + (size_t)r0 * DD;
  #pragma unroll
  for (int r = 0; r < 4; ++r) {
    ob[(lq * 4 + r) * DD + w * 32 + lr] = acc0[r];
    ob[(lq * 4 + r) * DD + w * 32 + 16 + lr] = acc1[r];
  }
}

extern "C" void kernel_launch(void* const* d_in, const int* in_sizes, int n_in,
                              void* d_out, int out_size, void* d_ws, size_t ws_size,
                              hipStream_t stream) {
  const float* hidden = (const float*)d_in[0];  // [64,128,128] fp32
  const int*   adj    = (const int*)d_in[1];    // [64,128,128] int32
  const float* amat   = (const float*)d_in[2];  // [128,4] fp32
  const float* Aattr  = (const float*)d_in[3];  // [64,128,1000] fp32
  const float* emb    = (const float*)d_in[4];  // [1000,128] fp32

  float* out0 = (float*)d_out;                  // output    [64,128,128] fp32
  float* out1 = out0 + (size_t)BB * NN * DD;    // attr_sess [64,128,128] fp32

  // d_ws layout (rebuilt every call): bf16 operand copies, ~21.2 MB total
  unsigned short* ET  = (unsigned short*)d_ws;        // [128][1024]
  unsigned short* HTg = ET + (size_t)DD * KPAD;       // [64][128][128] h^T
  unsigned short* Hg  = HTg + (size_t)BB * NN * DD;   // [64][128][128] h
  unsigned short* Asg = Hg + (size_t)BB * NN * DD;    // [512][16384] As tiles

  prep_kernel<<<BB + 32 + 256, 256, 0, stream>>>(hidden, emb, amat,
                                                 ET, HTg, Hg, Asg);
  attn_kernel<<<512, 256, 0, stream>>>(adj, HTg, Hg, Asg, out0);
  attr_kernel<<<512, 256, 0, stream>>>(Aattr, ET, out1);
}

// Round 6
// 123.971 us; speedup vs baseline: 1.0493x; 1.0080x over previous
//
#include <hip/hip_runtime.h>

// Problem constants (from reference setup_inputs)
#define BB 64
#define NN 128
#define DD 128
#define AA 1000
#define KPAD 1024
#define NEG_INF (-9.0e15f)

typedef __attribute__((ext_vector_type(8))) short short8;   // 8 bf16 MFMA frag
typedef __attribute__((ext_vector_type(4))) float floatx4;  // MFMA C/D frag
typedef __attribute__((ext_vector_type(4))) unsigned int uintx4;

__device__ __forceinline__ float bflo(unsigned int u) { return __uint_as_float(u << 16); }
__device__ __forceinline__ float bfhi(unsigned int u) { return __uint_as_float(u & 0xffff0000u); }
// truncating fp32->bf16 pack (cheap; ~2^-9 rel bias, fine vs threshold)
__device__ __forceinline__ unsigned int packbf(float f0, float f1) {
  return (__float_as_uint(f0) >> 16) | (__float_as_uint(f1) & 0xffff0000u);
}
// round-to-nearest-even fp32->bf16
__device__ __forceinline__ unsigned short bf_rne(float f) {
  unsigned int u = __float_as_uint(f);
  return (unsigned short)((u + 0x7fffu + ((u >> 16) & 1u)) >> 16);
}
__device__ __forceinline__ unsigned int packbf_rne(float f0, float f1) {
  return (unsigned int)bf_rne(f0) | ((unsigned int)bf_rne(f1) << 16);
}
__device__ __forceinline__ short8 u2s(uintx4 v) {
  union { uintx4 u; short8 s; } x; x.u = v; return x.s;
}

// ---------------------------------------------------------------------------
// Prep (96 blocks x 256):
//   blocks  0..63 : HTg[b][d][i] = bf16(h^T)  and  Hg[b][i][d] = bf16(h)
//                   (Hg unswizzled: fused reads 16B frags straight from L2)
//   blocks 64..95 : ET[c][k] = bf16(emb[k][c]) via coalesced rows + LDS
//                   transpose, k zero-padded to 1024.
// No Asg (R4/R5 refuted: the 16.8MB write+read roundtrip cost ~20us net).
// ---------------------------------------------------------------------------
__global__ __launch_bounds__(256) void prep_kernel(
    const float* __restrict__ hidden, const float* __restrict__ emb,
    unsigned short* __restrict__ ET, unsigned short* __restrict__ HTg,
    unsigned short* __restrict__ Hg)
{
  __shared__ float hsf[NN * 129];
  const int t = threadIdx.x;
  const int bid = blockIdx.x;
  if (bid < BB) {
    const float* hb = hidden + (size_t)bid * NN * DD;
    #pragma unroll
    for (int u = 0; u < 16; ++u) {
      int e = u * 1024 + t * 4;
      float4 v = *reinterpret_cast<const float4*>(hb + e);
      int r = e >> 7, c = e & 127;
      float* d = &hsf[r * 129 + c];
      d[0] = v.x; d[1] = v.y; d[2] = v.z; d[3] = v.w;
    }
    __syncthreads();
    unsigned short* ht16 = HTg + (size_t)bid * NN * DD;
    #pragma unroll
    for (int u = 0; u < 8; ++u) {  // transpose via LDS columns
      int e = u * 2048 + t * 8;
      int dI = e >> 7, il = e & 127;
      float x[8];
      #pragma unroll
      for (int j = 0; j < 8; ++j) x[j] = hsf[(il + j) * 129 + dI];
      uintx4 o;
      o.x = packbf_rne(x[0], x[1]); o.y = packbf_rne(x[2], x[3]);
      o.z = packbf_rne(x[4], x[5]); o.w = packbf_rne(x[6], x[7]);
      *reinterpret_cast<uintx4*>(ht16 + e) = o;
    }
    // Hg: row-major bf16 h, unswizzled
    unsigned short* hg = Hg + (size_t)bid * NN * DD;
    #pragma unroll
    for (int u = 0; u < 8; ++u) {
      int id = u * 256 + t;
      int r = id >> 4, c = id & 15;
      const float* src = &hsf[r * 129 + c * 8];
      uintx4 o;
      o.x = packbf_rne(src[0], src[1]); o.y = packbf_rne(src[2], src[3]);
      o.z = packbf_rne(src[4], src[5]); o.w = packbf_rne(src[6], src[7]);
      *reinterpret_cast<uintx4*>(hg + r * 128 + c * 8) = o;
    }
  } else {
    // ET transpose: 32 blocks, 32 k-rows each, coalesced emb reads.
    const int k0 = (bid - BB) * 32;
    #pragma unroll
    for (int u = 0; u < 4; ++u) {
      int e = u * 1024 + t * 4;
      int r = e >> 7, c = e & 127;
      float4 z = {0.f, 0.f, 0.f, 0.f};
      float4 v = (k0 + r < AA)
          ? *reinterpret_cast<const float4*>(emb + (size_t)(k0 + r) * DD + c) : z;
      float* d = &hsf[r * 129 + c];
      d[0] = v.x; d[1] = v.y; d[2] = v.z; d[3] = v.w;
    }
    __syncthreads();
    int c = t >> 1, j0 = (t & 1) * 16;
    float x[16];
    #pragma unroll
    for (int j = 0; j < 16; ++j) x[j] = hsf[(j0 + j) * 129 + c];
    uintx4 o0, o1;
    o0.x = packbf_rne(x[0], x[1]);  o0.y = packbf_rne(x[2], x[3]);
    o0.z = packbf_rne(x[4], x[5]);  o0.w = packbf_rne(x[6], x[7]);
    o1.x = packbf_rne(x[8], x[9]);  o1.y = packbf_rne(x[10], x[11]);
    o1.z = packbf_rne(x[12], x[13]); o1.w = packbf_rne(x[14], x[15]);
    unsigned short* dst = ET + (size_t)c * KPAD + k0 + j0;
    *reinterpret_cast<uintx4*>(dst) = o0;
    *reinterpret_cast<uintx4*>(dst + 8) = o1;
  }
}

// ---------------------------------------------------------------------------
// Fused kernel, grid = 1024 = 512 attn + 512 attr, LDS 36864 B -> exactly
// 4 blocks/CU, so the ENTIRE grid is co-resident in ONE generation (1024
// slots), ~2 attn + 2 attr blocks per CU: attr's Aattr HBM stream overlaps
// attn's latency phases machine-wide with zero sequential generations.
// attn: no Hs tile — As-build source and QK B-frags are 16B L2 reads from
// prep's bf16 Hg (pattern validated in R5); full 32KB As -> single QK pass
// (R0-proven inner loop). attr: zero LDS, zero barriers, 2-deep register
// prefetch (fits the 128-VGPR cap of launch_bounds(256,4); R4 proved the
// failure mode is VGPR starvation, so both branches stay ~<=110 live).
// ---------------------------------------------------------------------------
struct AttnSmem {
  union {
    __align__(16) unsigned short As[4 * 16 * 256];  // 32768 B (QK phase)
    struct {
      __align__(16) float Sa[16 * 129];             // 8256 B (post-QK)
      __align__(16) unsigned short W[16 * 128];     // 4096 B (softmax out)
    } sw;
  } u2;
  __align__(16) float saf[4 * 256];                 // 4096 B scale table
};  // 36864 B -> 4 blocks/CU

__global__ __launch_bounds__(256, 4) void fused_kernel(
    const int* __restrict__ adj, const float* __restrict__ amat,
    const float* __restrict__ Aattr, const unsigned short* __restrict__ ET,
    const unsigned short* __restrict__ HTg, const unsigned short* __restrict__ Hg,
    float* __restrict__ out0, float* __restrict__ out1)
{
  __shared__ AttnSmem s;
  const int t = threadIdx.x;
  const int L = t & 63, w = t >> 6;     // wave w = j-quarter / d-quarter / n-quarter
  const int lr = L & 15, lq = L >> 4;   // MFMA lane coords
  // XCD-chunked bijective swizzle (1024 % 8 == 0). XCD x hosts wids
  // [128x,128x+128): attn tiles for batches [8x,8x+8) (Hg/HTg/adj L2-local)
  // + a contiguous 4MB Aattr chunk. wid parity mixes types per CU.
  const int bid = blockIdx.x;
  const int wid = (bid & 7) * 128 + (bid >> 3);
  const int tile = wid >> 1;

  if ((wid & 1) == 0) {
    // ================= attn tile: b, 16 rows at i0 =================
    const int b = tile >> 3;
    const int i0 = (tile & 7) * 16;
    const unsigned short* hg = Hg + (size_t)b * NN * DD;

    // ---- issue ALL long-latency loads up front (independent) ----
    // As-build source: rows i0..i0+15 of Hg, 8x16B per thread
    uintx4 asrc[8];
    #pragma unroll
    for (int u = 0; u < 8; ++u) {
      int id = u * 256 + t;
      int ii = (id >> 5) & 15, c = id & 31;      // k = id>>9 reuses same src
      asrc[u] = *reinterpret_cast<const uintx4*>(
          hg + (i0 + ii) * 128 + (c & 15) * 8);
    }
    // adj
    const int* adjb = adj + ((size_t)b * NN + i0) * NN;
    int adjv[8];
    #pragma unroll
    for (int nt = 0; nt < 2; ++nt)
      #pragma unroll
      for (int r = 0; r < 4; ++r)
        adjv[nt * 4 + r] = adjb[(lq * 4 + r) * NN + w * 32 + nt * 16 + lr];
    // QK B-frags from Hg
    uintx4 hvq[2][4];
    #pragma unroll
    for (int nt = 0; nt < 2; ++nt)
      #pragma unroll
      for (int q = 0; q < 4; ++q) {
        int jrow = w * 32 + nt * 16 + lr;
        hvq[nt][q] = *reinterpret_cast<const uintx4*>(
            hg + jrow * 128 + (lq + 4 * q) * 8);
      }
    // scale table: saf[k][d]=0.6*a[d][k], saf[k][128+d]=0.4*a[d][k]
    {
      float v1 = amat[t], v2 = amat[t + 256];
      int dI = t >> 2, k = t & 3;
      s.saf[k * 256 + dI] = 0.6f * v1;
      s.saf[k * 256 + 128 + dI] = 0.4f * v1;
      s.saf[k * 256 + 64 + dI] = 0.6f * v2;
      s.saf[k * 256 + 192 + dI] = 0.4f * v2;
    }
    __syncthreads();  // saf ready

    // ---- build full As[k][ii][d'] (d'<128: h*0.6a_k ; d'>=128: |h|*0.4a_k) ----
    #pragma unroll
    for (int u = 0; u < 8; ++u) {
      int id = u * 256 + t;
      int k = id >> 9, ii = (id >> 5) & 15, c = id & 31;
      uintx4 hv = asrc[u];
      if (c & 16) {
        hv.x &= 0x7fff7fffu; hv.y &= 0x7fff7fffu;
        hv.z &= 0x7fff7fffu; hv.w &= 0x7fff7fffu;
      }
      const float* sf = &s.saf[k * 256 + c * 8];
      uintx4 o;
      o.x = packbf(bflo(hv.x) * sf[0], bfhi(hv.x) * sf[1]);
      o.y = packbf(bflo(hv.y) * sf[2], bfhi(hv.y) * sf[3]);
      o.z = packbf(bflo(hv.z) * sf[4], bfhi(hv.z) * sf[5]);
      o.w = packbf(bflo(hv.w) * sf[6], bfhi(hv.w) * sf[7]);
      *reinterpret_cast<uintx4*>(&s.u2.As[k * 4096 + ii * 256 + ((c ^ ii) << 3)]) = o;
    }
    __syncthreads();  // As staged

    // ---- QK: pure ds_read_b128 + MFMA (R0-proven), bfr from hvq regs ----
    floatx4 acc[4][2];
    #pragma unroll
    for (int k = 0; k < 4; ++k)
      #pragma unroll
      for (int nt = 0; nt < 2; ++nt) acc[k][nt] = floatx4{0.f, 0.f, 0.f, 0.f};

    #pragma unroll
    for (int kt = 0; kt < 8; ++kt) {
      int ca = lq + 4 * kt;
      short8 afr[4];
      #pragma unroll
      for (int k = 0; k < 4; ++k)
        afr[k] = *reinterpret_cast<const short8*>(
            &s.u2.As[k * 4096 + lr * 256 + ((ca ^ lr) << 3)]);
      #pragma unroll
      for (int nt = 0; nt < 2; ++nt) {
        uintx4 hv = hvq[nt][kt & 3];
        if (kt >= 4) {
          hv.x &= 0x7fff7fffu; hv.y &= 0x7fff7fffu;
          hv.z &= 0x7fff7fffu; hv.w &= 0x7fff7fffu;
        }
        short8 bfr = u2s(hv);
        #pragma unroll
        for (int k = 0; k < 4; ++k)
          acc[k][nt] = __builtin_amdgcn_mfma_f32_16x16x32_bf16(
              afr[k], bfr, acc[k][nt], 0, 0, 0);
      }
    }
    __syncthreads();  // As reads done; Sa/W may overlay

    // PV B-frags issued here: latency hides under selection/softmax
    short8 pvb[2][4];
    const unsigned short* ht = HTg + (size_t)b * NN * DD;
    #pragma unroll
    for (int nt = 0; nt < 2; ++nt)
      #pragma unroll
      for (int kt = 0; kt < 4; ++kt) {
        int dI = w * 32 + nt * 16 + lr;
        pvb[nt][kt] = *reinterpret_cast<const short8*>(
            ht + dI * 128 + kt * 32 + lq * 8);
      }

    // ---- in-register adj selection; C/D: col=lane&15, row=(lane>>4)*4+reg ----
    #pragma unroll
    for (int nt = 0; nt < 2; ++nt)
      #pragma unroll
      for (int r = 0; r < 4; ++r) {
        int ii = lq * 4 + r;
        int j = w * 32 + nt * 16 + lr;
        int ad = adjv[nt * 4 + r];
        float al = NEG_INF;
        al = (ad == 1) ? acc[0][nt][r] : al;
        al = (ad == 2) ? acc[1][nt][r] : al;
        al = (ad == 3) ? acc[2][nt][r] : al;
        al = (ad == 4) ? acc[3][nt][r] : al;
        s.u2.sw.Sa[ii * 129 + j] = al;
      }
    __syncthreads();

    // ---- softmax: one full row per wave (lane holds j=L and j=L+64) ----
    #pragma unroll
    for (int p = 0; p < 4; ++p) {
      int ii = w * 4 + p;
      float a1 = s.u2.sw.Sa[ii * 129 + L];
      float a2 = s.u2.sw.Sa[ii * 129 + 64 + L];
      float m = fmaxf(a1, a2);
      #pragma unroll
      for (int off = 32; off > 0; off >>= 1) m = fmaxf(m, __shfl_xor(m, off, 64));
      // all-masked row: a-m==0 -> uniform (matches jax); clamp guards exp
      float e1 = __expf(fmaxf(a1 - m, -80.f));
      float e2 = __expf(fmaxf(a2 - m, -80.f));
      float ss = e1 + e2;
      #pragma unroll
      for (int off = 32; off > 0; off >>= 1) ss += __shfl_xor(ss, off, 64);
      float inv = 1.f / ss;
      int j2 = L + 64;
      s.u2.sw.W[ii * 128 + (((L >> 3) ^ ii) << 3) + (L & 7)] = bf_rne(e1 * inv);
      s.u2.sw.W[ii * 128 + (((j2 >> 3) ^ ii) << 3) + (j2 & 7)] = bf_rne(e2 * inv);
    }
    __syncthreads();

    // ---- PV ----
    floatx4 oacc0 = floatx4{0.f, 0.f, 0.f, 0.f};
    floatx4 oacc1 = floatx4{0.f, 0.f, 0.f, 0.f};
    #pragma unroll
    for (int kt = 0; kt < 4; ++kt) {
      int c = lq + 4 * kt;
      short8 wf = *reinterpret_cast<const short8*>(
          &s.u2.sw.W[lr * 128 + ((c ^ lr) << 3)]);
      oacc0 = __builtin_amdgcn_mfma_f32_16x16x32_bf16(wf, pvb[0][kt], oacc0, 0, 0, 0);
      oacc1 = __builtin_amdgcn_mfma_f32_16x16x32_bf16(wf, pvb[1][kt], oacc1, 0, 0, 0);
    }
    float* ob = out0 + ((size_t)b * NN + i0) * DD;
    #pragma unroll
    for (int r = 0; r < 4; ++r) {
      ob[(lq * 4 + r) * DD + w * 32 + lr] = oacc0[r];
      ob[(lq * 4 + r) * DD + w * 32 + 16 + lr] = oacc1[r];
    }
  } else {
    // ===== attr tile: 16 rows at r0, zero LDS / zero barriers, 2-deep =====
    const int r0 = tile * 16;
    const float* arow = Aattr + (size_t)(r0 + lr) * AA;   // per-lane A row
    const unsigned short* e0 = ET + (size_t)(w * 32 + lr) * KPAD;
    const unsigned short* e1 = ET + (size_t)(w * 32 + 16 + lr) * KPAD;

    float4 paA[4], paB[4];   // [ks*2 + half] fp32 A pieces
    uintx4 peA[4], peB[4];   // [ks*2 + nt]   bf16 ET frags
    floatx4 acc0 = floatx4{0.f, 0.f, 0.f, 0.f};
    floatx4 acc1 = floatx4{0.f, 0.f, 0.f, 0.f};

#define AFETCH(PA, PE, IT) do {                                              \
    int kb = (IT) * 64;                                                      \
    float4 z = {0.f, 0.f, 0.f, 0.f};                                        \
    _Pragma("unroll")                                                        \
    for (int ks = 0; ks < 2; ++ks) {                                         \
      int k4 = kb + (lq + 4 * ks) * 8;                                       \
      PA[ks * 2 + 0] = (k4 < AA) ? *reinterpret_cast<const float4*>(arow + k4) : z; \
      PA[ks * 2 + 1] = (k4 + 4 < AA) ? *reinterpret_cast<const float4*>(arow + k4 + 4) : z; \
      PE[ks * 2 + 0] = *reinterpret_cast<const uintx4*>(e0 + k4);            \
      PE[ks * 2 + 1] = *reinterpret_cast<const uintx4*>(e1 + k4);            \
    }                                                                        \
  } while (0)

#define ABODY(PA, PE, IT) do {                                               \
    short8 af0, af1, bf00, bf01, bf10, bf11;                                 \
    {                                                                        \
      uintx4 a0, a1;                                                         \
      a0.x = packbf(PA[0].x, PA[0].y); a0.y = packbf(PA[0].z, PA[0].w);      \
      a0.z = packbf(PA[1].x, PA[1].y); a0.w = packbf(PA[1].z, PA[1].w);      \
      a1.x = packbf(PA[2].x, PA[2].y); a1.y = packbf(PA[2].z, PA[2].w);      \
      a1.z = packbf(PA[3].x, PA[3].y); a1.w = packbf(PA[3].z, PA[3].w);      \
      af0 = u2s(a0); af1 = u2s(a1);                                          \
      bf00 = u2s(PE[0]); bf01 = u2s(PE[1]);                                  \
      bf10 = u2s(PE[2]); bf11 = u2s(PE[3]);                                  \
    }                                                                        \
    if ((IT) < 14) AFETCH(PA, PE, (IT) + 2);                                 \
    acc0 = __builtin_amdgcn_mfma_f32_16x16x32_bf16(af0, bf00, acc0, 0, 0, 0); \
    acc1 = __builtin_amdgcn_mfma_f32_16x16x32_bf16(af0, bf01, acc1, 0, 0, 0); \
    acc0 = __builtin_amdgcn_mfma_f32_16x16x32_bf16(af1, bf10, acc0, 0, 0, 0); \
    acc1 = __builtin_amdgcn_mfma_f32_16x16x32_bf16(af1, bf11, acc1, 0, 0, 0); \
  } while (0)

    AFETCH(paA, peA, 0);
    AFETCH(paB, peB, 1);
    #pragma unroll
    for (int ith = 0; ith < 8; ++ith) {
      ABODY(paA, peA, 2 * ith);
      ABODY(paB, peB, 2 * ith + 1);
    }
#undef AFETCH
#undef ABODY

    float* ob = out1 + (size_t)r0 * DD;
    #pragma unroll
    for (int r = 0; r < 4; ++r) {
      ob[(lq * 4 + r) * DD + w * 32 + lr] = acc0[r];
      ob[(lq * 4 + r) * DD + w * 32 + 16 + lr] = acc1[r];
    }
  }
}

extern "C" void kernel_launch(void* const* d_in, const int* in_sizes, int n_in,
                              void* d_out, int out_size, void* d_ws, size_t ws_size,
                              hipStream_t stream) {
  const float* hidden = (const float*)d_in[0];  // [64,128,128] fp32
  const int*   adj    = (const int*)d_in[1];    // [64,128,128] int32
  const float* amat   = (const float*)d_in[2];  // [128,4] fp32
  const float* Aattr  = (const float*)d_in[3];  // [64,128,1000] fp32
  const float* emb    = (const float*)d_in[4];  // [1000,128] fp32

  float* out0 = (float*)d_out;                  // output    [64,128,128] fp32
  float* out1 = out0 + (size_t)BB * NN * DD;    // attr_sess [64,128,128] fp32

  // d_ws layout (rebuilt every call): bf16 operand copies, ~4.5 MB
  unsigned short* ET  = (unsigned short*)d_ws;        // [128][1024]
  unsigned short* HTg = ET + (size_t)DD * KPAD;       // [64][128][128] h^T
  unsigned short* Hg  = HTg + (size_t)BB * NN * DD;   // [64][128][128] h

  prep_kernel<<<BB + 32, 256, 0, stream>>>(hidden, emb, ET, HTg, Hg);
  fused_kernel<<<1024, 256, 0, stream>>>(adj, amat, Aattr, ET, HTg, Hg,
                                         out0, out1);
}

// Round 7
// 106.333 us; speedup vs baseline: 1.2234x; 1.1659x over previous
//
#include <hip/hip_runtime.h>

// Problem constants (from reference setup_inputs)
#define BB 64
#define NN 128
#define DD 128
#define AA 1000
#define KPAD 1024
#define NEG_INF (-9.0e15f)

typedef __attribute__((ext_vector_type(8))) short short8;   // 8 bf16 MFMA frag
typedef __attribute__((ext_vector_type(4))) float floatx4;  // MFMA C/D frag
typedef __attribute__((ext_vector_type(4))) unsigned int uintx4;
typedef __attribute__((ext_vector_type(2))) unsigned int uintx2;
typedef __attribute__((ext_vector_type(4))) int intx4;

__device__ __forceinline__ float bflo(unsigned int u) { return __uint_as_float(u << 16); }
__device__ __forceinline__ float bfhi(unsigned int u) { return __uint_as_float(u & 0xffff0000u); }
// truncating fp32->bf16 pack (cheap; ~2^-9 rel bias, fine vs threshold)
__device__ __forceinline__ unsigned int packbf(float f0, float f1) {
  return (__float_as_uint(f0) >> 16) | (__float_as_uint(f1) & 0xffff0000u);
}
// round-to-nearest-even fp32->bf16
__device__ __forceinline__ unsigned short bf_rne(float f) {
  unsigned int u = __float_as_uint(f);
  return (unsigned short)((u + 0x7fffu + ((u >> 16) & 1u)) >> 16);
}
__device__ __forceinline__ unsigned int packbf_rne(float f0, float f1) {
  return (unsigned int)bf_rne(f0) | ((unsigned int)bf_rne(f1) << 16);
}
__device__ __forceinline__ short8 u2s(uintx4 v) {
  union { uintx4 u; short8 s; } x; x.u = v; return x.s;
}

// ---------------------------------------------------------------------------
// Prep (96 blocks x 256): blocks 0..63 -> HTg[b][d][i] = bf16(h[b]^T);
// blocks 64..95 -> ET[c][k] = bf16(emb[k][c]) via coalesced row loads + LDS
// transpose, k zero-padded to 1024.
// ---------------------------------------------------------------------------
__global__ __launch_bounds__(256) void prep_kernel(
    const float* __restrict__ hidden, const float* __restrict__ emb,
    unsigned short* __restrict__ ET, unsigned short* __restrict__ HTg)
{
  __shared__ float hsf[NN * 129];
  const int t = threadIdx.x;
  const int bid = blockIdx.x;
  if (bid < BB) {
    const float* hb = hidden + (size_t)bid * NN * DD;
    #pragma unroll
    for (int u = 0; u < 16; ++u) {
      int e = u * 1024 + t * 4;
      float4 v = *reinterpret_cast<const float4*>(hb + e);
      int r = e >> 7, c = e & 127;
      float* d = &hsf[r * 129 + c];
      d[0] = v.x; d[1] = v.y; d[2] = v.z; d[3] = v.w;
    }
    __syncthreads();
    unsigned short* ht16 = HTg + (size_t)bid * NN * DD;
    #pragma unroll
    for (int u = 0; u < 8; ++u) {  // transpose via LDS columns
      int e = u * 2048 + t * 8;
      int dI = e >> 7, il = e & 127;
      float x[8];
      #pragma unroll
      for (int j = 0; j < 8; ++j) x[j] = hsf[(il + j) * 129 + dI];
      uintx4 o;
      o.x = packbf_rne(x[0], x[1]); o.y = packbf_rne(x[2], x[3]);
      o.z = packbf_rne(x[4], x[5]); o.w = packbf_rne(x[6], x[7]);
      *reinterpret_cast<uintx4*>(ht16 + e) = o;
    }
  } else {
    // ET transpose: 32 blocks, 32 k-rows each, coalesced emb reads.
    const int k0 = (bid - BB) * 32;
    #pragma unroll
    for (int u = 0; u < 4; ++u) {
      int e = u * 1024 + t * 4;
      int r = e >> 7, c = e & 127;
      float4 z = {0.f, 0.f, 0.f, 0.f};
      float4 v = (k0 + r < AA)
          ? *reinterpret_cast<const float4*>(emb + (size_t)(k0 + r) * DD + c) : z;
      float* d = &hsf[r * 129 + c];
      d[0] = v.x; d[1] = v.y; d[2] = v.z; d[3] = v.w;
    }
    __syncthreads();
    int c = t >> 1, j0 = (t & 1) * 16;
    float x[16];
    #pragma unroll
    for (int j = 0; j < 16; ++j) x[j] = hsf[(j0 + j) * 129 + c];
    uintx4 o0, o1;
    o0.x = packbf_rne(x[0], x[1]);  o0.y = packbf_rne(x[2], x[3]);
    o0.z = packbf_rne(x[4], x[5]);  o0.w = packbf_rne(x[6], x[7]);
    o1.x = packbf_rne(x[8], x[9]);  o1.y = packbf_rne(x[10], x[11]);
    o1.z = packbf_rne(x[12], x[13]); o1.w = packbf_rne(x[14], x[15]);
    unsigned short* dst = ET + (size_t)c * KPAD + k0 + j0;
    *reinterpret_cast<uintx4*>(dst) = o0;
    *reinterpret_cast<uintx4*>(dst + 8) = o1;
  }
}

// ---------------------------------------------------------------------------
// Fused kernel, grid = 512 (2 blocks/CU at 77.8 KB LDS): every block does one
// 16-row attn tile AND one 16-row attr-GEMM tile; parity (wid&1) flips the
// order so ~half the machine streams Aattr from HBM while the other half does
// the L2/LDS-bound attn phases. This is the best-measured structure (R1,
// 103.2us); the only delta vs R1 is coalesced adj staging via LDS (the adj
// tile is one contiguous 8KB range; was 8 scattered 4B gathers/thread).
// ---------------------------------------------------------------------------
struct AttnSmem {
  __align__(16) unsigned short Hs[NN * 128];        // 32768 B bf16 h (swizzled)
  union {
    __align__(16) unsigned short As[4 * 16 * 256];  // 32768 B (QK phase only)
    struct {
      __align__(16) float Sa[16 * 129];             // 8256 B (post-QK)
      __align__(16) unsigned short W[16 * 128];     // 4096 B (softmax out)
    } sw;
  } u2;
  __align__(16) float saf[4 * 256];                 // 4096 B scale table
  __align__(16) int Aj[16 * 128];                   // 8192 B coalesced adj tile
};  // 77824 B

#define BK 64
struct AttrSmem {
  __align__(16) unsigned short ETs[2][DD * BK];     // 32768 B
  __align__(16) unsigned short As2[2][16 * BK];     // 4096 B (16-row tile)
};  // 36864 B

union FusedSmem { AttnSmem a; AttrSmem g; };        // 77824 B -> 2 blocks/CU

__device__ __forceinline__ void attn_body(
    AttnSmem& s, const float* __restrict__ hidden,
    const int* __restrict__ adj, const float* __restrict__ amat,
    const unsigned short* __restrict__ HTg, float* __restrict__ out0,
    int wid)
{
  const int t = threadIdx.x;
  const int L = t & 63, w = t >> 6;     // wave w = j-quarter / d-quarter
  const int lr = L & 15, lq = L >> 4;   // MFMA lane coords
  const int b = wid >> 3;
  const int i0 = (wid & 7) * 16;

  // ---- adj stage: the 16x128 tile is CONTIGUOUS (row stride == row len) ----
  const int* adjb = adj + ((size_t)b * NN + i0) * NN;
  #pragma unroll
  for (int u = 0; u < 2; ++u) {
    int e = u * 1024 + t * 4;
    *reinterpret_cast<intx4*>(&s.Aj[e]) =
        *reinterpret_cast<const intx4*>(adjb + e);
  }

  // ---- stage Hs from fp32 hidden (convert in flight; swizzle c^(row&15)) ----
  const float* hb = hidden + (size_t)b * NN * DD;
  #pragma unroll
  for (int u = 0; u < 8; ++u) {
    int id = u * 256 + t;
    int r = id >> 4, c = id & 15;
    const float* src = hb + r * 128 + c * 8;
    float4 v0 = *reinterpret_cast<const float4*>(src);
    float4 v1 = *reinterpret_cast<const float4*>(src + 4);
    uintx4 o;
    o.x = packbf_rne(v0.x, v0.y); o.y = packbf_rne(v0.z, v0.w);
    o.z = packbf_rne(v1.x, v1.y); o.w = packbf_rne(v1.z, v1.w);
    *reinterpret_cast<uintx4*>(&s.Hs[r * 128 + ((c ^ (r & 15)) << 3)]) = o;
  }
  // ---- scale table: saf[k][d]=0.6*a[d][k], saf[k][128+d]=0.4*a[d][k] ----
  {
    float v1 = amat[t], v2 = amat[t + 256];
    int dI = t >> 2, k = t & 3;
    s.saf[k * 256 + dI] = 0.6f * v1;
    s.saf[k * 256 + 128 + dI] = 0.4f * v1;
    s.saf[k * 256 + 64 + dI] = 0.6f * v2;
    s.saf[k * 256 + 192 + dI] = 0.4f * v2;
  }
  __syncthreads();

  // ---- build As[k][i][d'] (d'<128: h*0.6a_k ; d'>=128: |h|*0.4a_k) ----
  #pragma unroll
  for (int u = 0; u < 8; ++u) {
    int id = u * 256 + t;
    int k = id >> 9, ii = (id >> 5) & 15, c = id & 31;
    int srow = i0 + ii;
    int dchunk = c & 15;
    uintx4 hv = *reinterpret_cast<const uintx4*>(
        &s.Hs[srow * 128 + ((dchunk ^ (srow & 15)) << 3)]);
    if (c & 16) {
      hv.x &= 0x7fff7fffu; hv.y &= 0x7fff7fffu;
      hv.z &= 0x7fff7fffu; hv.w &= 0x7fff7fffu;
    }
    const float* sf = &s.saf[k * 256 + c * 8];
    uintx4 o;
    o.x = packbf(bflo(hv.x) * sf[0], bfhi(hv.x) * sf[1]);
    o.y = packbf(bflo(hv.y) * sf[2], bfhi(hv.y) * sf[3]);
    o.z = packbf(bflo(hv.z) * sf[4], bfhi(hv.z) * sf[5]);
    o.w = packbf(bflo(hv.w) * sf[6], bfhi(hv.w) * sf[7]);
    *reinterpret_cast<uintx4*>(&s.u2.As[k * 4096 + ii * 256 + ((c ^ ii) << 3)]) = o;
  }
  __syncthreads();

  // ---- QK: all 4 edge-type scores in one K'=256 GEMM, 8 MFMA/step ----
  floatx4 acc[4][2];
  #pragma unroll
  for (int k = 0; k < 4; ++k)
    #pragma unroll
    for (int nt = 0; nt < 2; ++nt) acc[k][nt] = floatx4{0.f, 0.f, 0.f, 0.f};

  #pragma unroll
  for (int kt = 0; kt < 8; ++kt) {
    int ca = lq + 4 * kt;
    short8 afr[4];
    #pragma unroll
    for (int k = 0; k < 4; ++k)
      afr[k] = *reinterpret_cast<const short8*>(
          &s.u2.As[k * 4096 + lr * 256 + ((ca ^ lr) << 3)]);
    int cb = lq + 4 * (kt & 3);
    short8 bfr[2];
    #pragma unroll
    for (int nt = 0; nt < 2; ++nt) {
      int jrow = w * 32 + nt * 16 + lr;
      uintx4 hv = *reinterpret_cast<const uintx4*>(
          &s.Hs[jrow * 128 + ((cb ^ (jrow & 15)) << 3)]);
      if (kt >= 4) {
        hv.x &= 0x7fff7fffu; hv.y &= 0x7fff7fffu;
        hv.z &= 0x7fff7fffu; hv.w &= 0x7fff7fffu;
      }
      bfr[nt] = u2s(hv);
    }
    #pragma unroll
    for (int k = 0; k < 4; ++k)
      #pragma unroll
      for (int nt = 0; nt < 2; ++nt)
        acc[k][nt] = __builtin_amdgcn_mfma_f32_16x16x32_bf16(
            afr[k], bfr[nt], acc[k][nt], 0, 0, 0);
  }
  __syncthreads();  // all As reads done; Sa/W may now overlay As

  // ---- prefetch PV B-frags from HTg (hides under selection/softmax) ----
  short8 pvb[2][4];
  const unsigned short* ht = HTg + (size_t)b * NN * DD;
  #pragma unroll
  for (int nt = 0; nt < 2; ++nt)
    #pragma unroll
    for (int kt = 0; kt < 4; ++kt) {
      int dI = w * 32 + nt * 16 + lr;
      pvb[nt][kt] = *reinterpret_cast<const short8*>(ht + dI * 128 + kt * 32 + lq * 8);
    }

  // ---- in-register adj selection; C/D: col=lane&15, row=(lane>>4)*4+reg ----
  #pragma unroll
  for (int nt = 0; nt < 2; ++nt)
    #pragma unroll
    for (int r = 0; r < 4; ++r) {
      int ii = lq * 4 + r;
      int j = w * 32 + nt * 16 + lr;
      int ad = s.Aj[ii * 128 + j];
      float al = NEG_INF;
      al = (ad == 1) ? acc[0][nt][r] : al;
      al = (ad == 2) ? acc[1][nt][r] : al;
      al = (ad == 3) ? acc[2][nt][r] : al;
      al = (ad == 4) ? acc[3][nt][r] : al;
      s.u2.sw.Sa[ii * 129 + j] = al;
    }
  __syncthreads();

  // ---- softmax: one full row per wave (lane holds j=L and j=L+64) ----
  #pragma unroll
  for (int p = 0; p < 4; ++p) {
    int ii = w * 4 + p;
    float a1 = s.u2.sw.Sa[ii * 129 + L];
    float a2 = s.u2.sw.Sa[ii * 129 + 64 + L];
    float m = fmaxf(a1, a2);
    #pragma unroll
    for (int off = 32; off > 0; off >>= 1) m = fmaxf(m, __shfl_xor(m, off, 64));
    // all-masked row: a-m==0 -> uniform (matches jax); clamp guards exp
    float e1 = __expf(fmaxf(a1 - m, -80.f));
    float e2 = __expf(fmaxf(a2 - m, -80.f));
    float ss = e1 + e2;
    #pragma unroll
    for (int off = 32; off > 0; off >>= 1) ss += __shfl_xor(ss, off, 64);
    float inv = 1.f / ss;
    int j2 = L + 64;
    s.u2.sw.W[ii * 128 + (((L >> 3) ^ ii) << 3) + (L & 7)] = bf_rne(e1 * inv);
    s.u2.sw.W[ii * 128 + (((j2 >> 3) ^ ii) << 3) + (j2 & 7)] = bf_rne(e2 * inv);
  }
  __syncthreads();

  // ---- PV: out[i][d] = sum_j W[i,j] * h[j,d] (B from HTg prefetch) ----
  floatx4 oacc[2];
  oacc[0] = floatx4{0.f, 0.f, 0.f, 0.f};
  oacc[1] = floatx4{0.f, 0.f, 0.f, 0.f};
  #pragma unroll
  for (int kt = 0; kt < 4; ++kt) {
    int c = lq + 4 * kt;
    short8 wf = *reinterpret_cast<const short8*>(
        &s.u2.sw.W[lr * 128 + ((c ^ lr) << 3)]);
    #pragma unroll
    for (int nt = 0; nt < 2; ++nt)
      oacc[nt] = __builtin_amdgcn_mfma_f32_16x16x32_bf16(
          wf, pvb[nt][kt], oacc[nt], 0, 0, 0);
  }
  float* ob = out0 + ((size_t)b * NN + i0) * DD;
  #pragma unroll
  for (int nt = 0; nt < 2; ++nt)
    #pragma unroll
    for (int r = 0; r < 4; ++r)
      ob[(lq * 4 + r) * DD + w * 32 + nt * 16 + lr] = oacc[nt][r];
}

// 16-row attr tile, 2-deep register prefetch (named sets A/B — no runtime-
// indexed ext_vector arrays, which would spill to scratch).
__device__ __forceinline__ void attr_body(
    AttrSmem& s, const float* __restrict__ Aattr,
    const unsigned short* __restrict__ ET, float* __restrict__ out1,
    int wid)
{
  const int t = threadIdx.x;
  const int L = t & 63, w = t >> 6;
  const int lr = L & 15, lq = L >> 4;
  const int r0 = wid * 16;

  const int ar = t >> 4;          // A row 0..15 (16 threads per row)
  const int ak = (t & 15) * 4;    // k offset within BK (float4 granularity)
  const int ec = t >> 1, ej0 = (t & 1) * 4;
  const float* arow = Aattr + (size_t)(r0 + ar) * AA;
  const unsigned short* erow = ET + (size_t)ec * KPAD;

  float4 paA, paB;
  uintx4 peA[4], peB[4];

#define ATTR_FETCH(PA, PE, IT) do {                                          \
    int kb = (IT) * BK; int k4 = kb + ak;                                    \
    float4 z = {0.f, 0.f, 0.f, 0.f};                                        \
    PA = (k4 < AA) ? *reinterpret_cast<const float4*>(arow + k4) : z;        \
    _Pragma("unroll")                                                        \
    for (int q = 0; q < 4; ++q)                                              \
      PE[q] = *reinterpret_cast<const uintx4*>(erow + kb + (ej0 + q) * 8);   \
  } while (0)

#define ATTR_STAGE(PA, PE, BUF) do {                                         \
    uintx2 o; o.x = packbf(PA.x, PA.y); o.y = packbf(PA.z, PA.w);            \
    int cidx = ak >> 3, half = ak & 7;                                       \
    *reinterpret_cast<uintx2*>(                                              \
        &s.As2[BUF][ar * BK + ((cidx ^ (ar & 7)) << 3) + half]) = o;         \
    _Pragma("unroll")                                                        \
    for (int q = 0; q < 4; ++q)                                              \
      *reinterpret_cast<uintx4*>(                                            \
          &s.ETs[BUF][ec * BK + (((ej0 + q) ^ (ec & 7)) << 3)]) = PE[q];     \
  } while (0)

#define ATTR_COMPUTE(BUF) do {                                               \
    _Pragma("unroll")                                                        \
    for (int ks = 0; ks < 2; ++ks) {                                         \
      int c = lq + 4 * ks;                                                   \
      short8 af = *reinterpret_cast<const short8*>(                          \
          &s.As2[BUF][lr * BK + ((c ^ (lr & 7)) << 3)]);                     \
      _Pragma("unroll")                                                      \
      for (int nt = 0; nt < 2; ++nt) {                                       \
        int n = w * 32 + nt * 16 + lr;                                       \
        short8 bf = *reinterpret_cast<const short8*>(                        \
            &s.ETs[BUF][n * BK + ((c ^ (n & 7)) << 3)]);                     \
        acc[nt] = __builtin_amdgcn_mfma_f32_16x16x32_bf16(                   \
            af, bf, acc[nt], 0, 0, 0);                                       \
      }                                                                      \
    }                                                                        \
  } while (0)

  floatx4 acc[2];
  acc[0] = floatx4{0.f, 0.f, 0.f, 0.f};
  acc[1] = floatx4{0.f, 0.f, 0.f, 0.f};

  ATTR_FETCH(paA, peA, 0);
  ATTR_FETCH(paB, peB, 1);
  for (int ith = 0; ith < 8; ++ith) {
    // Safe: a thread reaches STAGE(buf) only after the barrier that proves
    // every thread finished the previous COMPUTE on that buffer.
    ATTR_STAGE(paA, peA, 0);
    __syncthreads();
    if (ith < 7) ATTR_FETCH(paA, peA, 2 * ith + 2);  // lands ~2 iters later
    ATTR_COMPUTE(0);
    ATTR_STAGE(paB, peB, 1);
    __syncthreads();
    if (ith < 7) ATTR_FETCH(paB, peB, 2 * ith + 3);
    ATTR_COMPUTE(1);
  }
#undef ATTR_FETCH
#undef ATTR_STAGE
#undef ATTR_COMPUTE

  float* ob = out1 + (size_t)r0 * DD;
  #pragma unroll
  for (int nt = 0; nt < 2; ++nt)
    #pragma unroll
    for (int r = 0; r < 4; ++r)
      ob[(lq * 4 + r) * DD + w * 32 + nt * 16 + lr] = acc[nt][r];
}

__global__ __launch_bounds__(256, 2) void fused_kernel(
    const float* __restrict__ hidden, const int* __restrict__ adj,
    const float* __restrict__ amat, const float* __restrict__ Aattr,
    const unsigned short* __restrict__ ET, const unsigned short* __restrict__ HTg,
    float* __restrict__ out0, float* __restrict__ out1)
{
  __shared__ FusedSmem sm;
  // XCD-chunked swizzle (512 % 8 == 0 -> bijective): the 8 blocks sharing a
  // batch b land on one XCD's L2 (hidden[b] 64 KB + HTg[b] 32 KB resident).
  const int bid = blockIdx.x;
  const int wid = (bid & 7) * 64 + (bid >> 3);
  if (wid & 1) {
    attn_body(sm.a, hidden, adj, amat, HTg, out0, wid);
    __syncthreads();  // LDS union handoff (skewed waves)
    attr_body(sm.g, Aattr, ET, out1, wid);
  } else {
    attr_body(sm.g, Aattr, ET, out1, wid);
    __syncthreads();
    attn_body(sm.a, hidden, adj, amat, HTg, out0, wid);
  }
}

extern "C" void kernel_launch(void* const* d_in, const int* in_sizes, int n_in,
                              void* d_out, int out_size, void* d_ws, size_t ws_size,
                              hipStream_t stream) {
  const float* hidden = (const float*)d_in[0];  // [64,128,128] fp32
  const int*   adj    = (const int*)d_in[1];    // [64,128,128] int32
  const float* amat   = (const float*)d_in[2];  // [128,4] fp32
  const float* Aattr  = (const float*)d_in[3];  // [64,128,1000] fp32
  const float* emb    = (const float*)d_in[4];  // [1000,128] fp32

  float* out0 = (float*)d_out;                  // output    [64,128,128] fp32
  float* out1 = out0 + (size_t)BB * NN * DD;    // attr_sess [64,128,128] fp32

  // d_ws layout (rebuilt every call): bf16 operand copies
  unsigned short* ET  = (unsigned short*)d_ws;      // [128][1024]
  unsigned short* HTg = ET + (size_t)DD * KPAD;     // [64][128][128] h^T

  prep_kernel<<<BB + 32, 256, 0, stream>>>(hidden, emb, ET, HTg);
  fused_kernel<<<512, 256, 0, stream>>>(hidden, adj, amat, Aattr, ET, HTg,
                                        out0, out1);
}